// Round 12
// baseline (120.406 us; speedup 1.0000x reference)
//
#include <hip/hip_runtime.h>
#include <cfloat>
#include <cmath>

#define N_NODES 20000
#define MAXD 32
#define F 128

// ---------------- stage 1: trimmed-mean aggregation (R11 verbatim) -----------
// CRITICAL invariants (measured):
//  * node index must be blockIdx-derived (scalar) — threadIdx-derived i =>
//    ~10x VALU blowup (R6: 415us).
//  * private arrays must be pow2-sized with static indices — non-pow2 triggers
//    promote-to-LDS + scratch spill (R8: LDS_Block=10240, 140us).
//  * 1 node / 128-thread block. Exact-n templates (R11): compile-time b,
//    direct-register rank extraction, pad-pruned sort network -> 57 -> ~38us.
//  * Likely near the random-gather HBM floor now (~61 MB at ~1.6 TB/s eff).

template <int SZ, int NV>
__device__ __forceinline__ void oe_sort_n(float (&a)[SZ]) {
#pragma unroll
  for (int p = 1; p < SZ; p <<= 1) {
#pragma unroll
    for (int q = p; q >= 1; q >>= 1) {
#pragma unroll
      for (int j = q % p; j <= SZ - 1 - q; j += 2 * q) {
#pragma unroll
        for (int i = 0; i < q; ++i) {
          int x = i + j, y = i + j + q;
          if (y < NV && (x / (2 * p)) == (y / (2 * p))) {  // y<NV ⊆ y<SZ
            float mn = fminf(a[x], a[y]);
            float mx = fmaxf(a[x], a[y]);
            a[x] = mn;
            a[y] = mx;
          }
        }
      }
    }
  }
}

// b = max(min(n/2 - (1-n%2), (int)floor_f32(n*0.45f)), 1) — f32 mult matches
// jnp exactly (e.g. n=20: 20*0.449999988f = 8.9999998 -> 8, not 9).
template <int N>
struct TrimB {
  static constexpr int b_raw = N / 2 - (1 - (N & 1));
  static constexpr int b_cap = (int)((float)N * 0.45f);  // trunc == floor (pos)
  static constexpr int b_min = b_raw < b_cap ? b_raw : b_cap;
  static constexpr int value = b_min > 1 ? b_min : 1;
};

// Exact trimmed sum, exact-n specialization. Stable-rank semantics match
// jnp.argsort (ties by slot). Fast path: no equal-key run straddles either
// trim boundary -> pure value test. Slow path (rare): exact stable-rank scan.
template <int SZ, int N>
__device__ __forceinline__ float trimmed_sum_n(const float* __restrict__ h,
                                               const float* __restrict__ norm,
                                               const int* __restrict__ nbr_row,
                                               int f) {
  constexpr int B = TrimB<N>::value;
  constexpr int NB = N - B;

  float ko[SZ];
  float nrm[SZ];  // block-uniform -> SGPRs
  float k[SZ];
#pragma unroll
  for (int d = 0; d < N; ++d) {
    int src = nbr_row[d];       // scalar load
    nrm[d] = norm[src];         // scalar load
    ko[d] = h[src * F + f];     // vector load, coalesced 256B/wave
    k[d] = ko[d];
  }
#pragma unroll
  for (int d = N; d < SZ; ++d) k[d] = FLT_MAX;  // pads sort past all valid keys

  oe_sort_n<SZ, N>(k);

  const float lo  = k[B];       // compile-time positions -> direct reg reads
  const float hi  = k[NB - 1];
  const float lom = k[B - 1];
  const float him = k[NB];

  float sum = 0.f;
  if ((lom < lo) & (hi < him)) {
#pragma unroll
    for (int d = 0; d < N; ++d) {
      bool keep = (ko[d] >= lo) & (ko[d] <= hi);
      sum = fmaf(keep ? ko[d] : 0.f, nrm[d], sum);
    }
  } else {
    int c_lt_lo = 0, c_lt_hi = 0;
#pragma unroll
    for (int d = 0; d < N; ++d) {
      c_lt_lo += (ko[d] < lo) ? 1 : 0;
      c_lt_hi += (ko[d] < hi) ? 1 : 0;
    }
    int run_lo = 0, run_hi = 0;
#pragma unroll
    for (int d = 0; d < N; ++d) {
      const float kd = ko[d];
      const float m = kd * nrm[d];
      const bool eql = (kd == lo);
      const bool eqh = (kd == hi);
      const bool lh = (lo < hi);
      const bool btw = (kd > lo) & (kd < hi);
      const int r_lo = c_lt_lo + run_lo;  // stable rank if kd==lo
      const int r_hi = c_lt_hi + run_hi;  // stable rank if kd==hi
      const bool inc = btw
                     | (eql & (r_lo >= B) & (lh | (r_lo < NB)))
                     | (lh & eqh & (r_hi < NB));
      sum += inc ? m : 0.f;
      run_lo += eql ? 1 : 0;
      run_hi += eqh ? 1 : 0;
    }
  }
  return sum;
}

__global__ __launch_bounds__(128) void gcn_stage1(const float* __restrict__ h,
                                                  const float* __restrict__ norm,
                                                  const int* __restrict__ nbr,
                                                  const int* __restrict__ deg,
                                                  float* __restrict__ accum) {
  const int i = blockIdx.x;       // MUST stay blockIdx-derived (scalar)
  const int f = threadIdx.x;
  const int n = deg[i];           // scalar
  const float ni = norm[i];
  const float hif = h[i * F + f];
  const int idx = i * F + f;

  if (n <= 3) {  // N_NEIGH_THRESHOLD branch
    accum[idx] = (float)n * hif * ni * ni;
    return;
  }

  const int* nbr_row = nbr + i * MAXD;
  float ts;
  int b;
  switch (n) {  // scalar switch; each case fully compile-time specialized
#define TS_CASE(NN, SS) \
    case NN: ts = trimmed_sum_n<SS, NN>(h, norm, nbr_row, f); b = TrimB<NN>::value; break;
    TS_CASE(4, 4)
    TS_CASE(5, 8) TS_CASE(6, 8) TS_CASE(7, 8) TS_CASE(8, 8)
    TS_CASE(9, 16) TS_CASE(10, 16) TS_CASE(11, 16) TS_CASE(12, 16)
    TS_CASE(13, 16) TS_CASE(14, 16) TS_CASE(15, 16) TS_CASE(16, 16)
    TS_CASE(17, 32) TS_CASE(18, 32) TS_CASE(19, 32) TS_CASE(20, 32)
    TS_CASE(21, 32) TS_CASE(22, 32) TS_CASE(23, 32) TS_CASE(24, 32)
    TS_CASE(25, 32) TS_CASE(26, 32) TS_CASE(27, 32) TS_CASE(28, 32)
    TS_CASE(29, 32) TS_CASE(30, 32) TS_CASE(31, 32)
    default: ts = trimmed_sum_n<32, 32>(h, norm, nbr_row, f); b = TrimB<32>::value; break;
#undef TS_CASE
  }

  accum[idx] = (ts + hif * ni * (float)(2 * b)) * ni;
}

// ---------------- stage 2: out = relu(accum @ W + bias) ----------------
// 64 rows x 128 cols per block (313 blocks), 256 threads, 8x4 thread tile.
// LDS model: per kq per wave 12 b128 (8 A + 4 W) = 144 LDS cyc vs 256 VALU cyc
// -> LDS:VALU demand 2.25:1 (was 3:1 at 4x4) => ~25% less LDS time per FMA.
// kc loop `unroll 1` — R5's spill came from FULL kc unroll (VGPR=256), not the
// 8x4 tile; with unroll 1 live set ≈ acc(32)+w(16)+a(4)+addr ≈ 90 VGPR.
__global__ __launch_bounds__(256) void gcn_gemm(const float* __restrict__ A,
                                                const float* __restrict__ W,
                                                const float* __restrict__ bias,
                                                float* __restrict__ out) {
  __shared__ float Ws[32 * F];   // 16 KB: k-chunk of W, [k][c]
  __shared__ float As[64 * 36];  // 9.2 KB: [row][k], pad 36 keeps 16B align
  const int t = threadIdx.x;
  const int tx = t & 31;         // col group: cols tx*4..tx*4+3
  const int ty = t >> 5;         // row group: rows ty*8..ty*8+7
  const int row0 = blockIdx.x * 64;

  float4 acc[8];
#pragma unroll
  for (int r = 0; r < 8; ++r) acc[r] = make_float4(0.f, 0.f, 0.f, 0.f);

#pragma unroll 1
  for (int kc = 0; kc < F; kc += 32) {
    __syncthreads();  // protect As/Ws from previous chunk's readers
    // stage A: 64 rows x 32 k = 512 float4, 2/thread, coalesced (guarded)
#pragma unroll
    for (int u = 0; u < 2; ++u) {
      int idx2 = u * 256 + t;
      int r = idx2 >> 3, q = idx2 & 7;
      int grow = row0 + r;
      float4 v = make_float4(0.f, 0.f, 0.f, 0.f);
      if (grow < N_NODES) v = *(const float4*)(A + grow * F + kc + q * 4);
      *(float4*)(As + r * 36 + q * 4) = v;
    }
    // stage W: 32 k x 128 c = 1024 float4, 4/thread, coalesced
#pragma unroll
    for (int u = 0; u < 4; ++u) {
      int idx2 = u * 256 + t;
      *(float4*)(Ws + idx2 * 4) = *(const float4*)(W + kc * F + idx2 * 4);
    }
    __syncthreads();
#pragma unroll
    for (int kq = 0; kq < 8; ++kq) {
      float4 w0 = *(const float4*)(Ws + (kq * 4 + 0) * F + tx * 4);
      float4 w1 = *(const float4*)(Ws + (kq * 4 + 1) * F + tx * 4);
      float4 w2 = *(const float4*)(Ws + (kq * 4 + 2) * F + tx * 4);
      float4 w3 = *(const float4*)(Ws + (kq * 4 + 3) * F + tx * 4);
#pragma unroll
      for (int r = 0; r < 8; ++r) {
        float4 a = *(const float4*)(As + (ty * 8 + r) * 36 + kq * 4);
        acc[r].x = fmaf(a.x, w0.x, acc[r].x);
        acc[r].y = fmaf(a.x, w0.y, acc[r].y);
        acc[r].z = fmaf(a.x, w0.z, acc[r].z);
        acc[r].w = fmaf(a.x, w0.w, acc[r].w);
        acc[r].x = fmaf(a.y, w1.x, acc[r].x);
        acc[r].y = fmaf(a.y, w1.y, acc[r].y);
        acc[r].z = fmaf(a.y, w1.z, acc[r].z);
        acc[r].w = fmaf(a.y, w1.w, acc[r].w);
        acc[r].x = fmaf(a.z, w2.x, acc[r].x);
        acc[r].y = fmaf(a.z, w2.y, acc[r].y);
        acc[r].z = fmaf(a.z, w2.z, acc[r].z);
        acc[r].w = fmaf(a.z, w2.w, acc[r].w);
        acc[r].x = fmaf(a.w, w3.x, acc[r].x);
        acc[r].y = fmaf(a.w, w3.y, acc[r].y);
        acc[r].z = fmaf(a.w, w3.z, acc[r].z);
        acc[r].w = fmaf(a.w, w3.w, acc[r].w);
      }
    }
  }

  float4 bv = *(const float4*)(bias + tx * 4);
#pragma unroll
  for (int r = 0; r < 8; ++r) {
    int grow = row0 + ty * 8 + r;
    if (grow < N_NODES) {
      float4 o;
      o.x = fmaxf(acc[r].x + bv.x, 0.f);
      o.y = fmaxf(acc[r].y + bv.y, 0.f);
      o.z = fmaxf(acc[r].z + bv.z, 0.f);
      o.w = fmaxf(acc[r].w + bv.w, 0.f);
      *(float4*)(out + grow * F + tx * 4) = o;
    }
  }
}

extern "C" void kernel_launch(void* const* d_in, const int* in_sizes, int n_in,
                              void* d_out, int out_size, void* d_ws, size_t ws_size,
                              hipStream_t stream) {
  const float* h = (const float*)d_in[0];
  const float* norm = (const float*)d_in[1];
  const float* weight = (const float*)d_in[2];
  const float* bias = (const float*)d_in[3];
  const int* nbr = (const int*)d_in[4];
  const int* deg = (const int*)d_in[5];
  float* out = (float*)d_out;
  float* accum = (float*)d_ws;  // 20000*128*4 = 10.24 MB scratch

  gcn_stage1<<<N_NODES, 128, 0, stream>>>(h, norm, nbr, deg, accum);
  gcn_gemm<<<(N_NODES + 63) / 64, 256, 0, stream>>>(accum, weight, bias, out);
}

// Round 13
// 111.991 us; speedup vs baseline: 1.0751x; 1.0751x over previous
//
#include <hip/hip_runtime.h>
#include <cfloat>
#include <cmath>

#define N_NODES 20000
#define MAXD 32
#define F 128

// ---------------- stage 1: trimmed-mean aggregation (R11 verbatim) -----------
// CRITICAL invariants (measured):
//  * node index must be blockIdx-derived (scalar) — threadIdx-derived i =>
//    ~10x VALU blowup (R6: 415us).
//  * private arrays must be pow2-sized with static indices — non-pow2 triggers
//    promote-to-LDS + scratch spill (R8: LDS_Block=10240, 140us).
//  * 1 node / 128-thread block. Exact-n templates (R11): compile-time b,
//    direct-register rank extraction, pad-pruned sort network -> 57 -> ~38us.
//  * Near the random-gather memory floor (~169 MB scattered 512B segments
//    at ~4.4 TB/s effective L2/L3).

template <int SZ, int NV>
__device__ __forceinline__ void oe_sort_n(float (&a)[SZ]) {
#pragma unroll
  for (int p = 1; p < SZ; p <<= 1) {
#pragma unroll
    for (int q = p; q >= 1; q >>= 1) {
#pragma unroll
      for (int j = q % p; j <= SZ - 1 - q; j += 2 * q) {
#pragma unroll
        for (int i = 0; i < q; ++i) {
          int x = i + j, y = i + j + q;
          if (y < NV && (x / (2 * p)) == (y / (2 * p))) {  // y<NV ⊆ y<SZ
            float mn = fminf(a[x], a[y]);
            float mx = fmaxf(a[x], a[y]);
            a[x] = mn;
            a[y] = mx;
          }
        }
      }
    }
  }
}

// b = max(min(n/2 - (1-n%2), (int)floor_f32(n*0.45f)), 1) — f32 mult matches
// jnp exactly (e.g. n=20: 20*0.449999988f = 8.9999998 -> 8, not 9).
template <int N>
struct TrimB {
  static constexpr int b_raw = N / 2 - (1 - (N & 1));
  static constexpr int b_cap = (int)((float)N * 0.45f);  // trunc == floor (pos)
  static constexpr int b_min = b_raw < b_cap ? b_raw : b_cap;
  static constexpr int value = b_min > 1 ? b_min : 1;
};

// Exact trimmed sum, exact-n specialization. Stable-rank semantics match
// jnp.argsort (ties by slot). Fast path: no equal-key run straddles either
// trim boundary -> pure value test. Slow path (rare): exact stable-rank scan.
template <int SZ, int N>
__device__ __forceinline__ float trimmed_sum_n(const float* __restrict__ h,
                                               const float* __restrict__ norm,
                                               const int* __restrict__ nbr_row,
                                               int f) {
  constexpr int B = TrimB<N>::value;
  constexpr int NB = N - B;

  float ko[SZ];
  float nrm[SZ];  // block-uniform -> SGPRs
  float k[SZ];
#pragma unroll
  for (int d = 0; d < N; ++d) {
    int src = nbr_row[d];       // scalar load
    nrm[d] = norm[src];         // scalar load
    ko[d] = h[src * F + f];     // vector load, coalesced 256B/wave
    k[d] = ko[d];
  }
#pragma unroll
  for (int d = N; d < SZ; ++d) k[d] = FLT_MAX;  // pads sort past all valid keys

  oe_sort_n<SZ, N>(k);

  const float lo  = k[B];       // compile-time positions -> direct reg reads
  const float hi  = k[NB - 1];
  const float lom = k[B - 1];
  const float him = k[NB];

  float sum = 0.f;
  if ((lom < lo) & (hi < him)) {
#pragma unroll
    for (int d = 0; d < N; ++d) {
      bool keep = (ko[d] >= lo) & (ko[d] <= hi);
      sum = fmaf(keep ? ko[d] : 0.f, nrm[d], sum);
    }
  } else {
    int c_lt_lo = 0, c_lt_hi = 0;
#pragma unroll
    for (int d = 0; d < N; ++d) {
      c_lt_lo += (ko[d] < lo) ? 1 : 0;
      c_lt_hi += (ko[d] < hi) ? 1 : 0;
    }
    int run_lo = 0, run_hi = 0;
#pragma unroll
    for (int d = 0; d < N; ++d) {
      const float kd = ko[d];
      const float m = kd * nrm[d];
      const bool eql = (kd == lo);
      const bool eqh = (kd == hi);
      const bool lh = (lo < hi);
      const bool btw = (kd > lo) & (kd < hi);
      const int r_lo = c_lt_lo + run_lo;  // stable rank if kd==lo
      const int r_hi = c_lt_hi + run_hi;  // stable rank if kd==hi
      const bool inc = btw
                     | (eql & (r_lo >= B) & (lh | (r_lo < NB)))
                     | (lh & eqh & (r_hi < NB));
      sum += inc ? m : 0.f;
      run_lo += eql ? 1 : 0;
      run_hi += eqh ? 1 : 0;
    }
  }
  return sum;
}

__global__ __launch_bounds__(128) void gcn_stage1(const float* __restrict__ h,
                                                  const float* __restrict__ norm,
                                                  const int* __restrict__ nbr,
                                                  const int* __restrict__ deg,
                                                  float* __restrict__ accum) {
  const int i = blockIdx.x;       // MUST stay blockIdx-derived (scalar)
  const int f = threadIdx.x;
  const int n = deg[i];           // scalar
  const float ni = norm[i];
  const float hif = h[i * F + f];
  const int idx = i * F + f;

  if (n <= 3) {  // N_NEIGH_THRESHOLD branch
    accum[idx] = (float)n * hif * ni * ni;
    return;
  }

  const int* nbr_row = nbr + i * MAXD;
  float ts;
  int b;
  switch (n) {  // scalar switch; each case fully compile-time specialized
#define TS_CASE(NN, SS) \
    case NN: ts = trimmed_sum_n<SS, NN>(h, norm, nbr_row, f); b = TrimB<NN>::value; break;
    TS_CASE(4, 4)
    TS_CASE(5, 8) TS_CASE(6, 8) TS_CASE(7, 8) TS_CASE(8, 8)
    TS_CASE(9, 16) TS_CASE(10, 16) TS_CASE(11, 16) TS_CASE(12, 16)
    TS_CASE(13, 16) TS_CASE(14, 16) TS_CASE(15, 16) TS_CASE(16, 16)
    TS_CASE(17, 32) TS_CASE(18, 32) TS_CASE(19, 32) TS_CASE(20, 32)
    TS_CASE(21, 32) TS_CASE(22, 32) TS_CASE(23, 32) TS_CASE(24, 32)
    TS_CASE(25, 32) TS_CASE(26, 32) TS_CASE(27, 32) TS_CASE(28, 32)
    TS_CASE(29, 32) TS_CASE(30, 32) TS_CASE(31, 32)
    default: ts = trimmed_sum_n<32, 32>(h, norm, nbr_row, f); b = TrimB<32>::value; break;
#undef TS_CASE
  }

  accum[idx] = (ts + hif * ni * (float)(2 * b)) * ni;
}

// ---------------- stage 2: out = relu(accum @ W + bias) (R8 verbatim) --------
// Empirical optimum of this family (~18 us): 256 threads, 32 rows x 128 cols
// per block (625 blocks), k-chunk=32, 4x4 tile, k-quad b128 inner loop.
// Measured dead ends: 8x4/64-row tile (R12: +4us — staging/tail bound, not
// LDS-throughput bound); full kc unroll (R5: VGPR=256 spill, 387MB scratch);
// wave-uniform global-A broadcast (R2: latency-serialized, +60us).
__global__ __launch_bounds__(256) void gcn_gemm(const float* __restrict__ A,
                                                const float* __restrict__ W,
                                                const float* __restrict__ bias,
                                                float* __restrict__ out) {
  __shared__ float Ws[32 * F];   // 16 KB: k-chunk of W, [k][c]
  __shared__ float As[32 * 36];  // 4.6 KB: [row][k], pad 36 keeps 16B align
  const int t = threadIdx.x;
  const int tx = t & 31;         // col group: cols tx*4..tx*4+3
  const int ty = t >> 5;         // row group: rows ty*4..ty*4+3
  const int row0 = blockIdx.x * 32;
  const int ar = t >> 3, ak = t & 7;  // A staging coords

  float acc[4][4];
#pragma unroll
  for (int r = 0; r < 4; ++r)
#pragma unroll
    for (int c = 0; c < 4; ++c) acc[r][c] = 0.f;

#pragma unroll 1
  for (int kc = 0; kc < F; kc += 32) {
    __syncthreads();  // protect As/Ws from previous chunk's readers
    // stage A: 32 rows x 32 k (1 float4/thread, coalesced)
    float4 av = *(const float4*)(A + (row0 + ar) * F + kc + ak * 4);
    *(float4*)(As + ar * 36 + ak * 4) = av;
    // stage W: 32 k x 128 c = 1024 float4 (4/thread, fully coalesced)
#pragma unroll
    for (int u = 0; u < 4; ++u) {
      int idx2 = u * 256 + t;
      *(float4*)(Ws + idx2 * 4) = *(const float4*)(W + kc * F + idx2 * 4);
    }
    __syncthreads();
#pragma unroll
    for (int kq = 0; kq < 8; ++kq) {
      float4 w0 = *(const float4*)(Ws + (kq * 4 + 0) * F + tx * 4);
      float4 w1 = *(const float4*)(Ws + (kq * 4 + 1) * F + tx * 4);
      float4 w2 = *(const float4*)(Ws + (kq * 4 + 2) * F + tx * 4);
      float4 w3 = *(const float4*)(Ws + (kq * 4 + 3) * F + tx * 4);
#pragma unroll
      for (int r = 0; r < 4; ++r) {
        float4 a = *(const float4*)(As + (ty * 4 + r) * 36 + kq * 4);  // broadcast
        acc[r][0] = fmaf(a.x, w0.x, acc[r][0]);
        acc[r][1] = fmaf(a.x, w0.y, acc[r][1]);
        acc[r][2] = fmaf(a.x, w0.z, acc[r][2]);
        acc[r][3] = fmaf(a.x, w0.w, acc[r][3]);
        acc[r][0] = fmaf(a.y, w1.x, acc[r][0]);
        acc[r][1] = fmaf(a.y, w1.y, acc[r][1]);
        acc[r][2] = fmaf(a.y, w1.z, acc[r][2]);
        acc[r][3] = fmaf(a.y, w1.w, acc[r][3]);
        acc[r][0] = fmaf(a.z, w2.x, acc[r][0]);
        acc[r][1] = fmaf(a.z, w2.y, acc[r][1]);
        acc[r][2] = fmaf(a.z, w2.z, acc[r][2]);
        acc[r][3] = fmaf(a.z, w2.w, acc[r][3]);
        acc[r][0] = fmaf(a.w, w3.x, acc[r][0]);
        acc[r][1] = fmaf(a.w, w3.y, acc[r][1]);
        acc[r][2] = fmaf(a.w, w3.z, acc[r][2]);
        acc[r][3] = fmaf(a.w, w3.w, acc[r][3]);
      }
    }
  }

  float4 bv = *(const float4*)(bias + tx * 4);
#pragma unroll
  for (int r = 0; r < 4; ++r) {
    float4 o;
    o.x = fmaxf(acc[r][0] + bv.x, 0.f);
    o.y = fmaxf(acc[r][1] + bv.y, 0.f);
    o.z = fmaxf(acc[r][2] + bv.z, 0.f);
    o.w = fmaxf(acc[r][3] + bv.w, 0.f);
    *(float4*)(out + (row0 + ty * 4 + r) * F + tx * 4) = o;
  }
}

extern "C" void kernel_launch(void* const* d_in, const int* in_sizes, int n_in,
                              void* d_out, int out_size, void* d_ws, size_t ws_size,
                              hipStream_t stream) {
  const float* h = (const float*)d_in[0];
  const float* norm = (const float*)d_in[1];
  const float* weight = (const float*)d_in[2];
  const float* bias = (const float*)d_in[3];
  const int* nbr = (const int*)d_in[4];
  const int* deg = (const int*)d_in[5];
  float* out = (float*)d_out;
  float* accum = (float*)d_ws;  // 20000*128*4 = 10.24 MB scratch

  gcn_stage1<<<N_NODES, 128, 0, stream>>>(h, norm, nbr, deg, accum);
  gcn_gemm<<<N_NODES / 32, 256, 0, stream>>>(accum, weight, bias, out);
}